// Round 6
// baseline (810.072 us; speedup 1.0000x reference)
//
#include <hip/hip_runtime.h>

#define HH 4096
#define BB 4096
#define IND 1024
#define NTOT 16777216   // 4096*4096
#define EPSV 1e-5f

typedef unsigned short u16;
typedef __bf16 bf16x8 __attribute__((ext_vector_type(8)));
typedef float f32x4 __attribute__((ext_vector_type(4)));
typedef u16 u16x8 __attribute__((ext_vector_type(8)));

__device__ __forceinline__ u16 f2bf(float f) {
    unsigned u = __builtin_bit_cast(unsigned, f);
    u += 0x7fffu + ((u >> 16) & 1u);
    return (u16)(u >> 16);
}
__device__ __forceinline__ float bf2f(u16 h) {
    return __builtin_bit_cast(float, ((unsigned)h) << 16);
}

// ---------------- batched f32 -> bf16 conversion (all 8 tensors, 1 launch) ----
#define C0 1048576u
#define C1 5242880u
#define C2 6291456u
#define C3 7340032u
#define C4 8388608u
#define C5 12582912u
#define C6 16777216u
#define C7 20971520u

__global__ __launch_bounds__(256) void cvt_all(
    const float* __restrict__ s0, const float* __restrict__ s1,
    const float* __restrict__ s2, const float* __restrict__ s3,
    const float* __restrict__ s4, const float* __restrict__ s5,
    const float* __restrict__ s6, const float* __restrict__ s7,
    u16* __restrict__ d0, u16* __restrict__ d1, u16* __restrict__ d2,
    u16* __restrict__ d3, u16* __restrict__ d4, u16* __restrict__ d5,
    u16* __restrict__ d6, u16* __restrict__ d7) {
    unsigned g = blockIdx.x * blockDim.x + threadIdx.x;
    const unsigned stride = gridDim.x * blockDim.x;
    for (; g < C7; g += stride) {
        const float* src; u16* dst; unsigned base;
        if (g < C1) {
            if (g < C0) { src = s0; dst = d0; base = 0; }
            else        { src = s1; dst = d1; base = C0; }
        } else if (g < C4) {
            if (g < C2)      { src = s2; dst = d2; base = C1; }
            else if (g < C3) { src = s3; dst = d3; base = C2; }
            else             { src = s4; dst = d4; base = C3; }
        } else {
            if (g < C5)      { src = s5; dst = d5; base = C4; }
            else if (g < C6) { src = s6; dst = d6; base = C5; }
            else             { src = s7; dst = d7; base = C6; }
        }
        const unsigned i4 = (g - base) * 4;
        f32x4 v = *(const f32x4*)(src + i4);
        unsigned p0 = (unsigned)f2bf(v[0]) | ((unsigned)f2bf(v[1]) << 16);
        unsigned p1 = (unsigned)f2bf(v[2]) | ((unsigned)f2bf(v[3]) << 16);
        *(uint2*)(dst + i4) = make_uint2(p0, p1);
    }
}

// ================= 256x256 8-phase GEMM (T2+T3+T4+T5) — R6 retry =================
// Identical schedule to R2 (HW-verified correct) MINUS the sched_barrier(0) /
// asm-lgkmcnt(0) pinning that produced the m141 regression signature (452 TF).
// C++ ds_reads let the compiler emit fine-grained lgkmcnt before MFMA use.
// Counted vmcnt(4) once per K-tile (P4) keeps 4 loads in flight across barriers.

template<int NT1, int NT2, int EPI>
__global__ __launch_bounds__(512, 2) void gemm256(
    const u16* __restrict__ A0, const u16* __restrict__ B0,
    const u16* __restrict__ A1, const u16* __restrict__ B1,
    const float* __restrict__ bias_a, const float* __restrict__ bias_b,
    const u16* __restrict__ rplane, u16* __restrict__ outp,
    float* __restrict__ partials) {
    constexpr int NT = NT1 + NT2;
    constexpr int LD0 = (EPI == 2) ? HH : IND;
    constexpr int LD1 = (EPI == 2) ? IND : HH;
    extern __shared__ __align__(16) u16 smem[];

    const int tid = threadIdx.x;
    const int l = tid & 63, w = tid >> 6;
    const int lr = l & 15, lq = l >> 4;
    const int wr = w >> 2;            // 0..1 : which 128-row half of C
    const int wn = w & 3;             // 0..3 : which 64-col strip
    const int bh = wn >> 1;           // which B half-tile
    const int m0 = blockIdx.x * 256, n0 = blockIdx.y * 256;
    const int linh = ((((lr << 6) | (lq << 4)) ^ ((lr & 8) << 2)) >> 1);
    const int bsub0 = (wn & 1) * 4;

    auto stageTile = [&](int tt, int mat, int h) {
        const u16* g = (tt < NT1) ? (mat ? B0 : A0) : (mat ? B1 : A1);
        const int ld = (tt < NT1) ? LD0 : LD1;
        const int kb = ((tt < NT1) ? tt : tt - NT1) * 64;
        const int rowbase = (mat ? n0 : m0) + h * 128;
        u16* base = smem + (tt & 1) * 32768 + mat * 16384 + h * 8192;
        const int wq = l << 4;
        const int lin = wq ^ (((wq >> 9) & 1) << 5);
        const int rl = lin >> 6;
        const int cl = (lin & 63) >> 1;
#pragma unroll
        for (int j = 0; j < 2; ++j) {
            const int sub = j * 8 + w;
            const int r = ((sub >> 1) << 4) | rl;
            const int c0 = ((sub & 1) << 5) | cl;
            const u16* ga = g + (size_t)(rowbase + r) * ld + (kb + c0);
            __builtin_amdgcn_global_load_lds(
                (const __attribute__((address_space(1))) unsigned*)ga,
                (__attribute__((address_space(3))) unsigned*)(base + (sub << 9)),
                16, 0, 0);
        }
    };

    f32x4 acc[8][4];
#pragma unroll
    for (int i = 0; i < 8; ++i)
#pragma unroll
        for (int j = 0; j < 4; ++j) {
            f32x4 zz = {0.f, 0.f, 0.f, 0.f};
            acc[i][j] = zz;
        }

    // prologue: tile0 full + tile1 A halves; wait until only the 4 newest remain
    stageTile(0, 0, 0); stageTile(0, 0, 1); stageTile(0, 1, 0); stageTile(0, 1, 1);
    stageTile(1, 0, 0); stageTile(1, 0, 1);
    asm volatile("s_waitcnt vmcnt(4)" ::: "memory");
    __builtin_amdgcn_s_barrier();

    bf16x8 a0[4][2], a1[4][2], bb[2][2];

    for (int t = 0; t < NT; ++t) {
        const u16* Ah = smem + (t & 1) * 32768 + wr * 8192 + linh;
        const u16* Bh = smem + (t & 1) * 32768 + 16384 + bh * 8192 + linh;
        int t1 = t + 1; if (t1 == NT) t1 = 0;
        int t2 = t + 2; if (t2 >= NT) t2 -= NT;

        // ---- P1: read A[half0] + B[n01]; prefetch B0(t+1); MFMA quad(0,0) ----
#pragma unroll
        for (int i = 0; i < 4; ++i)
#pragma unroll
            for (int ks = 0; ks < 2; ++ks)
                a0[i][ks] = *(const bf16x8*)(Ah + (i * 2 + ks) * 512);
#pragma unroll
        for (int n = 0; n < 2; ++n)
#pragma unroll
            for (int ks = 0; ks < 2; ++ks)
                bb[n][ks] = *(const bf16x8*)(Bh + ((bsub0 + n) * 2 + ks) * 512);
        stageTile(t1, 1, 0);
        __builtin_amdgcn_s_barrier();
        __builtin_amdgcn_s_setprio(1);
#pragma unroll
        for (int ks = 0; ks < 2; ++ks)
#pragma unroll
            for (int i = 0; i < 4; ++i)
#pragma unroll
                for (int n = 0; n < 2; ++n)
                    acc[i][n] = __builtin_amdgcn_mfma_f32_16x16x32_bf16(a0[i][ks], bb[n][ks], acc[i][n], 0, 0, 0);
        __builtin_amdgcn_s_setprio(0);
        __builtin_amdgcn_s_barrier();

        // ---- P2: read A[half1]; prefetch B1(t+1); MFMA quad(1,0) ----
#pragma unroll
        for (int i = 0; i < 4; ++i)
#pragma unroll
            for (int ks = 0; ks < 2; ++ks)
                a1[i][ks] = *(const bf16x8*)(Ah + 4096 + (i * 2 + ks) * 512);
        stageTile(t1, 1, 1);
        __builtin_amdgcn_s_barrier();
        __builtin_amdgcn_s_setprio(1);
#pragma unroll
        for (int ks = 0; ks < 2; ++ks)
#pragma unroll
            for (int i = 0; i < 4; ++i)
#pragma unroll
                for (int n = 0; n < 2; ++n)
                    acc[4 + i][n] = __builtin_amdgcn_mfma_f32_16x16x32_bf16(a1[i][ks], bb[n][ks], acc[4 + i][n], 0, 0, 0);
        __builtin_amdgcn_s_setprio(0);
        __builtin_amdgcn_s_barrier();

        // ---- P3: read B[n23]; prefetch A0(t+2)->cur; MFMA quad(0,1) ----
#pragma unroll
        for (int n = 0; n < 2; ++n)
#pragma unroll
            for (int ks = 0; ks < 2; ++ks)
                bb[n][ks] = *(const bf16x8*)(Bh + ((bsub0 + 2 + n) * 2 + ks) * 512);
        stageTile(t2, 0, 0);
        __builtin_amdgcn_s_barrier();
        __builtin_amdgcn_s_setprio(1);
#pragma unroll
        for (int ks = 0; ks < 2; ++ks)
#pragma unroll
            for (int i = 0; i < 4; ++i)
#pragma unroll
                for (int n = 0; n < 2; ++n)
                    acc[i][2 + n] = __builtin_amdgcn_mfma_f32_16x16x32_bf16(a0[i][ks], bb[n][ks], acc[i][2 + n], 0, 0, 0);
        __builtin_amdgcn_s_setprio(0);
        __builtin_amdgcn_s_barrier();

        // ---- P4: prefetch A1(t+2)->cur; vmcnt(4); MFMA quad(1,1) ----
        stageTile(t2, 0, 1);
        asm volatile("s_waitcnt vmcnt(4)" ::: "memory");
        __builtin_amdgcn_s_barrier();
        __builtin_amdgcn_s_setprio(1);
#pragma unroll
        for (int ks = 0; ks < 2; ++ks)
#pragma unroll
            for (int i = 0; i < 4; ++i)
#pragma unroll
                for (int n = 0; n < 2; ++n)
                    acc[4 + i][2 + n] = __builtin_amdgcn_mfma_f32_16x16x32_bf16(a1[i][ks], bb[n][ks], acc[4 + i][2 + n], 0, 0, 0);
        __builtin_amdgcn_s_setprio(0);
        if constexpr (EPI == 2) {
            if (t == NT1 - 1) {
                // acc = r * (acc + bias_a)   [registers + global r-plane only]
#pragma unroll
                for (int m8 = 0; m8 < 8; ++m8) {
                    const int rowb = m0 + wr * 128 + m8 * 16 + lq * 4;
#pragma unroll
                    for (int n8 = 0; n8 < 4; ++n8) {
                        const int col = n0 + wn * 64 + n8 * 16 + lr;
                        const float bias = bias_a[col];
#pragma unroll
                        for (int q = 0; q < 4; ++q) {
                            float rv = bf2f(rplane[(size_t)(rowb + q) * HH + col]);
                            acc[m8][n8][q] = rv * (acc[m8][n8][q] + bias);
                        }
                    }
                }
            }
        }
        __builtin_amdgcn_s_barrier();
    }

    // ---- epilogue ----
    if constexpr (EPI == 2) {
        float s = 0.f, ss = 0.f;
#pragma unroll
        for (int m8 = 0; m8 < 8; ++m8) {
            const int rowb = m0 + wr * 128 + m8 * 16 + lq * 4;
#pragma unroll
            for (int n8 = 0; n8 < 4; ++n8) {
                const int col = n0 + wn * 64 + n8 * 16 + lr;
                const float bias = bias_b[col];
#pragma unroll
                for (int q = 0; q < 4; ++q) {
                    float v = acc[m8][n8][q] + bias;
                    outp[(size_t)(rowb + q) * HH + col] = f2bf(v);
                    s += v; ss += v * v;
                }
            }
        }
#pragma unroll
        for (int off = 32; off; off >>= 1) {
            s += __shfl_down(s, off, 64);
            ss += __shfl_down(ss, off, 64);
        }
        asm volatile("s_waitcnt vmcnt(0)" ::: "memory");
        __syncthreads();
        float* red = (float*)smem;
        if (l == 0) { red[w * 2] = s; red[w * 2 + 1] = ss; }
        __syncthreads();
        if (tid == 0) {
            float S = 0.f, SS = 0.f;
#pragma unroll
            for (int i = 0; i < 8; ++i) { S += red[2 * i]; SS += red[2 * i + 1]; }
            const int bid = blockIdx.y * 16 + blockIdx.x;
            partials[2 * bid] = S;
            partials[2 * bid + 1] = SS;
        }
    } else {
#pragma unroll
        for (int m8 = 0; m8 < 8; ++m8) {
            const int rowb = m0 + wr * 128 + m8 * 16 + lq * 4;
#pragma unroll
            for (int n8 = 0; n8 < 4; ++n8) {
                const int col = n0 + wn * 64 + n8 * 16 + lr;
                const float bias = bias_a[col] + bias_b[col];
#pragma unroll
                for (int q = 0; q < 4; ++q) {
                    float v = 1.f / (1.f + __expf(-(acc[m8][n8][q] + bias)));
                    outp[(size_t)(rowb + q) * HH + col] = f2bf(v);
                }
            }
        }
        asm volatile("s_waitcnt vmcnt(0)" ::: "memory");
    }
}

// ---------------- stats reduce ----------------
__global__ void reduce_stats(const float* __restrict__ partials, int nblk,
                             const float* __restrict__ gamma, const float* __restrict__ beta,
                             float* __restrict__ stats) {
    __shared__ float rs[4], rss[4];
    int tid = threadIdx.x;
    float s = 0.f, ss = 0.f;
    for (int i = tid; i < nblk; i += blockDim.x) {
        s += partials[2 * i];
        ss += partials[2 * i + 1];
    }
#pragma unroll
    for (int off = 32; off; off >>= 1) {
        s += __shfl_down(s, off, 64);
        ss += __shfl_down(ss, off, 64);
    }
    if ((tid & 63) == 0) { rs[tid >> 6] = s; rss[tid >> 6] = ss; }
    __syncthreads();
    if (tid == 0) {
        float S = rs[0] + rs[1] + rs[2] + rs[3];
        float SS = rss[0] + rss[1] + rss[2] + rss[3];
        float mean = S / (float)NTOT;
        float var = SS / (float)NTOT - mean * mean;
        float scale = gamma[0] * rsqrtf(var + EPSV);
        stats[0] = scale;
        stats[1] = beta[0] - mean * scale;
    }
}

// ---------------- finalize: BN + blend + 4-way GEMV head ----------------
__global__ __launch_bounds__(256) void finalize(
    const u16* __restrict__ z, const u16* __restrict__ hpre,
    const float* __restrict__ hidden, const float* __restrict__ out_w,
    const float* __restrict__ out_b, const float* __restrict__ stats,
    float* __restrict__ d_out) {
    __shared__ float red[4][4];
    const int b = blockIdx.x, t = threadIdx.x;
    const float scale = stats[0], shift = stats[1];
    const size_t row = (size_t)b * HH;
    float so[4] = {0.f, 0.f, 0.f, 0.f};
#pragma unroll
    for (int jj = 0; jj < 2; ++jj) {
        int h0 = jj * 2048 + t * 8;
        u16x8 zv = *(const u16x8*)(z + row + h0);
        u16x8 hp = *(const u16x8*)(hpre + row + h0);
        f32x4 hd0 = *(const f32x4*)(hidden + row + h0);
        f32x4 hd1 = *(const f32x4*)(hidden + row + h0 + 4);
        f32x4 o0, o1;
#pragma unroll
        for (int e = 0; e < 8; ++e) {
            float zf = bf2f(zv[e]);
            float pv = bf2f(hp[e]) * scale + shift;
            pv = pv > 0.f ? pv : 0.f;
            float hf = (e < 4) ? hd0[e] : hd1[e - 4];
            float cs = (1.f - zf) * hf + zf * pv;
            if (e < 4) o0[e] = cs; else o1[e - 4] = cs;
#pragma unroll
            for (int o = 0; o < 4; ++o)
                so[o] += cs * __ldg(out_w + o * HH + h0 + e);
        }
        *(f32x4*)(d_out + row + h0) = o0;
        *(f32x4*)(d_out + row + h0 + 4) = o1;
    }
#pragma unroll
    for (int off = 32; off; off >>= 1)
#pragma unroll
        for (int o = 0; o < 4; ++o) so[o] += __shfl_down(so[o], off, 64);
    if ((t & 63) == 0)
#pragma unroll
        for (int o = 0; o < 4; ++o) red[t >> 6][o] = so[o];
    __syncthreads();
    if (t < 4) {
        float v = red[0][t] + red[1][t] + red[2][t] + red[3][t] + __ldg(out_b + t);
        d_out[(size_t)NTOT + (size_t)t * BB + b] = v;
    }
}

extern "C" void kernel_launch(void* const* d_in, const int* in_sizes, int n_in,
                              void* d_out, int out_size, void* d_ws, size_t ws_size,
                              hipStream_t stream) {
    const float* input = (const float*)d_in[0];
    const float* hidden = (const float*)d_in[3];
    const float* Wr_w = (const float*)d_in[4];  const float* Wr_b = (const float*)d_in[5];
    const float* Ur_w = (const float*)d_in[6];  const float* Ur_b = (const float*)d_in[7];
    const float* Wz_w = (const float*)d_in[8];  const float* Wz_b = (const float*)d_in[9];
    const float* Uz_w = (const float*)d_in[10]; const float* Uz_b = (const float*)d_in[11];
    const float* Wh_w = (const float*)d_in[12]; const float* Wh_b = (const float*)d_in[13];
    const float* Uh_w = (const float*)d_in[14]; const float* Uh_b = (const float*)d_in[15];
    const float* out_w = (const float*)d_in[16]; const float* out_b = (const float*)d_in[17];
    const float* gamma = (const float*)d_in[18]; const float* beta = (const float*)d_in[19];

    char* ws = (char*)d_ws;
    size_t off = 0;
    auto alloc = [&](size_t bytes) {
        void* p = ws + off;
        off = (off + bytes + 255) & ~(size_t)255;
        return p;
    };
    u16* xbf = (u16*)alloc((size_t)BB * IND * 2);
    u16* hbf = (u16*)alloc((size_t)BB * HH * 2);
    u16* wrp = (u16*)alloc((size_t)HH * IND * 2);
    u16* wzp = (u16*)alloc((size_t)HH * IND * 2);
    u16* whp = (u16*)alloc((size_t)HH * IND * 2);
    u16* urp = (u16*)alloc((size_t)HH * HH * 2);
    u16* uzp = (u16*)alloc((size_t)HH * HH * 2);
    u16* uhp = (u16*)alloc((size_t)HH * HH * 2);
    u16* zpl = (u16*)alloc((size_t)BB * HH * 2);
    u16* hpl = (u16*)alloc((size_t)BB * HH * 2);
    float* partials = (float*)alloc(2048 * sizeof(float));
    float* stats = (float*)alloc(16);

    // r-plane scratch in d_out's first 32MB (consumed by EPI_H before finalize
    // overwrites all of d_out) -- proven safe in R2/R4.
    u16* rpl = (u16*)d_out;

    hipFuncSetAttribute((const void*)gemm256<16, 64, 0>, hipFuncAttributeMaxDynamicSharedMemorySize, 131072);
    hipFuncSetAttribute((const void*)gemm256<16, 64, 1>, hipFuncAttributeMaxDynamicSharedMemorySize, 131072);
    hipFuncSetAttribute((const void*)gemm256<64, 16, 2>, hipFuncAttributeMaxDynamicSharedMemorySize, 131072);

    cvt_all<<<4096, 256, 0, stream>>>(input, hidden, Wr_w, Wz_w, Wh_w, Ur_w, Uz_w, Uh_w,
                                      xbf, hbf, wrp, wzp, whp, urp, uzp, uhp);

    gemm256<16, 64, 0><<<dim3(16, 16), 512, 131072, stream>>>(
        xbf, wrp, hbf, urp, Wr_b, Ur_b, nullptr, rpl, partials);
    gemm256<16, 64, 1><<<dim3(16, 16), 512, 131072, stream>>>(
        xbf, wzp, hbf, uzp, Wz_b, Uz_b, nullptr, zpl, partials);
    gemm256<64, 16, 2><<<dim3(16, 16), 512, 131072, stream>>>(
        hbf, uhp, xbf, whp, Uh_b, Wh_b, rpl, hpl, partials);

    reduce_stats<<<1, 256, 0, stream>>>(partials, 256, gamma, beta, stats);
    finalize<<<BB, 256, 0, stream>>>(zpl, hpl, hidden, out_w, out_b, stats, (float*)d_out);
}